// Round 1
// baseline (1302.905 us; speedup 1.0000x reference)
//
#include <hip/hip_runtime.h>
#include <stdint.h>

// Problem constants (B=2, S=2048 -> T=4096 tokens)
#define T_TOK 4096
#define Dm    1024
#define Em    8
#define Hm    4096

typedef __bf16 bf16x8 __attribute__((ext_vector_type(8)));
typedef float  f32x4  __attribute__((ext_vector_type(4)));

__device__ __forceinline__ unsigned short f2bf(float f) {
  union { float f; unsigned int u; } c; c.f = f;
  unsigned int u = c.u;
  unsigned int r = u + 0x7fffu + ((u >> 16) & 1u);  // round-to-nearest-even
  return (unsigned short)(r >> 16);
}

// ---------------- transpose + fp32->bf16 convert ----------------
// src: [E][R][C] fp32, dst: [E][C][R] bf16.  grid (C/32, R/32, E), block (32,8)
__global__ void transpose_cvt_kernel(const float* __restrict__ src,
                                     unsigned short* __restrict__ dst,
                                     int R, int C) {
  __shared__ float tile[32][33];
  const int e = blockIdx.z;
  const float* s = src + (size_t)e * R * C;
  unsigned short* d = dst + (size_t)e * R * C;
  const int c0 = blockIdx.x * 32, r0 = blockIdx.y * 32;
  for (int i = threadIdx.y; i < 32; i += 8)
    tile[i][threadIdx.x] = s[(size_t)(r0 + i) * C + c0 + threadIdx.x];
  __syncthreads();
  for (int i = threadIdx.y; i < 32; i += 8)
    d[(size_t)(c0 + i) * R + r0 + threadIdx.x] = f2bf(tile[threadIdx.x][i]);
}

// ---------------- x fp32 -> bf16 (straight cast) ----------------
__global__ void cvt_x_kernel(const float* __restrict__ x, unsigned short* __restrict__ xbf) {
  const int i = blockIdx.x * 256 + threadIdx.x;     // over float4 units
  float4 v = ((const float4*)x)[i];
  ushort4 o;
  o.x = f2bf(v.x); o.y = f2bf(v.y); o.z = f2bf(v.z); o.w = f2bf(v.w);
  ((ushort4*)xbf)[i] = o;
}

// ---------------- router: one wave per token ----------------
__global__ __launch_bounds__(256) void router_kernel(
    const float* __restrict__ x, const float* __restrict__ noise,
    const float* __restrict__ Wr, const float* __restrict__ br,
    const float* __restrict__ Wn, const float* __restrict__ bn,
    float* __restrict__ out_gating, float* __restrict__ gates,
    int* __restrict__ lists, int* __restrict__ counts) {
  const int wave = threadIdx.x >> 6, lane = threadIdx.x & 63;
  const int t = blockIdx.x * 4 + wave;
  const float* xt = x + (size_t)t * Dm;
  float accR[Em] = {}, accN[Em] = {};
  for (int d = lane; d < Dm; d += 64) {
    const float xv = xt[d];
    const float* wr = Wr + d * Em;
    const float* wn = Wn + d * Em;
#pragma unroll
    for (int e = 0; e < Em; e++) { accR[e] += xv * wr[e]; accN[e] += xv * wn[e]; }
  }
#pragma unroll
  for (int e = 0; e < Em; e++)
    for (int off = 32; off > 0; off >>= 1) {
      accR[e] += __shfl_down(accR[e], off, 64);
      accN[e] += __shfl_down(accN[e], off, 64);
    }
  if (lane == 0) {
    float lg[Em], ny[Em];
#pragma unroll
    for (int e = 0; e < Em; e++) {
      lg[e] = accR[e] + br[e];
      float nl = accN[e] + bn[e];
      float sp = fmaxf(nl, 0.f) + log1pf(expf(-fabsf(nl)));  // stable softplus
      ny[e] = lg[e] + noise[(size_t)t * Em + e] * sp;
    }
    // top-2, first-occurrence tie-break (matches lax.top_k)
    int i0 = 0;
#pragma unroll
    for (int e = 1; e < Em; e++) if (ny[e] > ny[i0]) i0 = e;
    int i1 = (i0 == 0) ? 1 : 0;
#pragma unroll
    for (int e = 0; e < Em; e++) if (e != i0 && ny[e] > ny[i1]) i1 = e;
    const float e1 = expf(ny[i1] - ny[i0]);
    const float g0 = 1.f / (1.f + e1), g1 = e1 / (1.f + e1);
#pragma unroll
    for (int e = 0; e < Em; e++) gates[(size_t)t * Em + e] = 0.f;
    gates[(size_t)t * Em + i0] = g0;
    gates[(size_t)t * Em + i1] = g1;
    // dense softmax of clean logits (output 2)
    float m = lg[0];
#pragma unroll
    for (int e = 1; e < Em; e++) m = fmaxf(m, lg[e]);
    float s = 0.f;
#pragma unroll
    for (int e = 0; e < Em; e++) s += expf(lg[e] - m);
#pragma unroll
    for (int e = 0; e < Em; e++) out_gating[(size_t)t * Em + e] = expf(lg[e] - m) / s;
    // append to expert lists
    int p0 = atomicAdd(&counts[i0], 1); lists[i0 * T_TOK + p0] = t;
    int p1 = atomicAdd(&counts[i1], 1); lists[i1 * T_TOK + p1] = t;
  }
}

// ---------------- GEMM1: hbuf[base+m][h] = relu(Xg[m] . W1t[h] + b1) ----------------
// A = xbf gathered rows [cnt x 1024], B = w1bf [E][H][D] (k-contig), C rows -> hbuf bf16
__global__ __launch_bounds__(256) void gemm1_kernel(
    const unsigned short* __restrict__ xbf, const unsigned short* __restrict__ w1bf,
    const float* __restrict__ b1, const int* __restrict__ counts,
    const int* __restrict__ lists, unsigned short* __restrict__ hbuf) {
  const int e = blockIdx.z;
  const int cnt = counts[e];
  const int m0 = blockIdx.x * 128;
  if (m0 >= cnt) return;
  const int n0 = blockIdx.y * 128;
  int base = 0;
  for (int i = 0; i < e; i++) base += counts[i];

  __shared__ __align__(16) unsigned short As[128 * 32];
  __shared__ __align__(16) unsigned short Bs[128 * 32];
  __shared__ int tok[128];

  const int tid = threadIdx.x;
  if (tid < 128) {
    int m = m0 + tid;
    tok[tid] = (m < cnt) ? lists[e * T_TOK + m] : 0;
  }
  __syncthreads();

  const int part = tid & 3;          // 16B chunk within 64B row
  const int r0 = tid >> 2;           // rows 0..63
  const int r1 = r0 + 64;
  const size_t gA0 = (size_t)tok[r0] * Dm + part * 8;
  const size_t gA1 = (size_t)tok[r1] * Dm + part * 8;
  const size_t gB0 = ((size_t)e * Hm + n0 + r0) * Dm + part * 8;
  const size_t gB1 = ((size_t)e * Hm + n0 + r1) * Dm + part * 8;

  const int lane = tid & 63, wave = tid >> 6;
  const int quad = lane >> 4, l15 = lane & 15;
  const int wm = (wave >> 1) * 64, wn = (wave & 1) * 64;

  f32x4 acc[4][4] = {};

  for (int k0 = 0; k0 < Dm; k0 += 32) {
    int4 a0 = *(const int4*)(xbf + gA0 + k0);
    int4 a1 = *(const int4*)(xbf + gA1 + k0);
    int4 b0 = *(const int4*)(w1bf + gB0 + k0);
    int4 b1v = *(const int4*)(w1bf + gB1 + k0);
    __syncthreads();
    *(int4*)(As + r0 * 32 + part * 8) = a0;
    *(int4*)(As + r1 * 32 + part * 8) = a1;
    *(int4*)(Bs + r0 * 32 + part * 8) = b0;
    *(int4*)(Bs + r1 * 32 + part * 8) = b1v;
    __syncthreads();
    bf16x8 af[4], bfv[4];
#pragma unroll
    for (int i = 0; i < 4; i++)
      af[i] = *(const bf16x8*)(As + (wm + i * 16 + l15) * 32 + quad * 8);
#pragma unroll
    for (int j = 0; j < 4; j++)
      bfv[j] = *(const bf16x8*)(Bs + (wn + j * 16 + l15) * 32 + quad * 8);
#pragma unroll
    for (int i = 0; i < 4; i++)
#pragma unroll
      for (int j = 0; j < 4; j++)
        acc[i][j] = __builtin_amdgcn_mfma_f32_16x16x32_bf16(af[i], bfv[j], acc[i][j], 0, 0, 0);
  }

#pragma unroll
  for (int i = 0; i < 4; i++)
#pragma unroll
    for (int r = 0; r < 4; r++) {
      const int ml = wm + i * 16 + quad * 4 + r;   // C/D row = quad*4+reg (m89/m91)
      const int m = m0 + ml;
      if (m < cnt) {
#pragma unroll
        for (int j = 0; j < 4; j++) {
          const int n = n0 + wn + j * 16 + l15;    // C/D col = lane&15
          float v = acc[i][j][r] + b1[(size_t)e * Hm + n];
          v = fmaxf(v, 0.f);
          hbuf[(size_t)(base + m) * Hm + n] = f2bf(v);
        }
      }
    }
}

// ---------------- GEMM2: out[t] += gate * (H[base+m] . W2t[d] + b2) ----------------
__global__ __launch_bounds__(256) void gemm2_kernel(
    const unsigned short* __restrict__ hbuf, const unsigned short* __restrict__ w2bf,
    const float* __restrict__ b2, const float* __restrict__ gates,
    const int* __restrict__ counts, const int* __restrict__ lists,
    float* __restrict__ out) {
  const int e = blockIdx.z;
  const int cnt = counts[e];
  const int m0 = blockIdx.x * 128;
  if (m0 >= cnt) return;
  const int n0 = blockIdx.y * 128;   // N = 1024
  int base = 0;
  for (int i = 0; i < e; i++) base += counts[i];

  __shared__ __align__(16) unsigned short As[128 * 32];
  __shared__ __align__(16) unsigned short Bs[128 * 32];

  const int tid = threadIdx.x;
  const int part = tid & 3;
  const int r0 = tid >> 2;
  const int r1 = r0 + 64;
  const int rowA0 = min(base + m0 + r0, 2 * T_TOK - 1);  // clamp: tail rows read junk, unused
  const int rowA1 = min(base + m0 + r1, 2 * T_TOK - 1);
  const size_t gA0 = (size_t)rowA0 * Hm + part * 8;
  const size_t gA1 = (size_t)rowA1 * Hm + part * 8;
  const size_t gB0 = ((size_t)e * Dm + n0 + r0) * Hm + part * 8;
  const size_t gB1 = ((size_t)e * Dm + n0 + r1) * Hm + part * 8;

  const int lane = tid & 63, wave = tid >> 6;
  const int quad = lane >> 4, l15 = lane & 15;
  const int wm = (wave >> 1) * 64, wn = (wave & 1) * 64;

  f32x4 acc[4][4] = {};

  for (int k0 = 0; k0 < Hm; k0 += 32) {
    int4 a0 = *(const int4*)(hbuf + gA0 + k0);
    int4 a1 = *(const int4*)(hbuf + gA1 + k0);
    int4 b0 = *(const int4*)(w2bf + gB0 + k0);
    int4 b1v = *(const int4*)(w2bf + gB1 + k0);
    __syncthreads();
    *(int4*)(As + r0 * 32 + part * 8) = a0;
    *(int4*)(As + r1 * 32 + part * 8) = a1;
    *(int4*)(Bs + r0 * 32 + part * 8) = b0;
    *(int4*)(Bs + r1 * 32 + part * 8) = b1v;
    __syncthreads();
    bf16x8 af[4], bfv[4];
#pragma unroll
    for (int i = 0; i < 4; i++)
      af[i] = *(const bf16x8*)(As + (wm + i * 16 + l15) * 32 + quad * 8);
#pragma unroll
    for (int j = 0; j < 4; j++)
      bfv[j] = *(const bf16x8*)(Bs + (wn + j * 16 + l15) * 32 + quad * 8);
#pragma unroll
    for (int i = 0; i < 4; i++)
#pragma unroll
      for (int j = 0; j < 4; j++)
        acc[i][j] = __builtin_amdgcn_mfma_f32_16x16x32_bf16(af[i], bfv[j], acc[i][j], 0, 0, 0);
  }

#pragma unroll
  for (int i = 0; i < 4; i++)
#pragma unroll
    for (int r = 0; r < 4; r++) {
      const int ml = wm + i * 16 + quad * 4 + r;
      const int m = m0 + ml;
      if (m < cnt) {
        const int t = lists[e * T_TOK + m];
        const float g = gates[(size_t)t * Em + e];
#pragma unroll
        for (int j = 0; j < 4; j++) {
          const int n = n0 + wn + j * 16 + l15;
          const float v = (acc[i][j][r] + b2[(size_t)e * Dm + n]) * g;
          atomicAdd(out + (size_t)t * Dm + n, v);
        }
      }
    }
}

extern "C" void kernel_launch(void* const* d_in, const int* in_sizes, int n_in,
                              void* d_out, int out_size, void* d_ws, size_t ws_size,
                              hipStream_t stream) {
  const float* x     = (const float*)d_in[0];
  const float* noise = (const float*)d_in[1];
  const float* Wr    = (const float*)d_in[2];
  const float* br    = (const float*)d_in[3];
  const float* Wn    = (const float*)d_in[4];
  const float* bn    = (const float*)d_in[5];
  const float* W1    = (const float*)d_in[6];
  const float* b1    = (const float*)d_in[7];
  const float* W2    = (const float*)d_in[8];
  const float* b2    = (const float*)d_in[9];

  float* out        = (float*)d_out;
  float* out_gating = out + (size_t)T_TOK * Dm;

  // ws layout (~210 MB total)
  char* ws = (char*)d_ws;
  unsigned short* w1bf = (unsigned short*)(ws);                 //  64 MiB  [E][H][D] bf16
  unsigned short* w2bf = (unsigned short*)(ws + 67108864);      //  64 MiB  [E][D][H] bf16
  unsigned short* xbf  = (unsigned short*)(ws + 134217728);     //   8 MiB  [T][D] bf16
  unsigned short* hbuf = (unsigned short*)(ws + 142606336);     //  64 MiB  [2T][H] bf16
  float* gates         = (float*)(ws + 209715200);              // 128 KiB  [T][E]
  int*   lists         = (int*)(ws + 209846272);                // 128 KiB  [E][T]
  int*   counts        = (int*)(ws + 209977344);                //  32 B    [E]

  hipMemsetAsync(counts, 0, Em * sizeof(int), stream);
  hipMemsetAsync(d_out, 0, (size_t)T_TOK * Dm * sizeof(float), stream);

  // weights -> bf16 transposed (k-contiguous for MFMA B operand)
  transpose_cvt_kernel<<<dim3(Hm / 32, Dm / 32, Em), dim3(32, 8), 0, stream>>>(W1, w1bf, Dm, Hm);
  transpose_cvt_kernel<<<dim3(Dm / 32, Hm / 32, Em), dim3(32, 8), 0, stream>>>(W2, w2bf, Hm, Dm);
  cvt_x_kernel<<<(T_TOK * Dm / 4) / 256, 256, 0, stream>>>(x, xbf);

  router_kernel<<<T_TOK / 4, 256, 0, stream>>>(x, noise, Wr, br, Wn, bn,
                                               out_gating, gates, lists, counts);

  gemm1_kernel<<<dim3(32, Hm / 128, Em), 256, 0, stream>>>(xbf, w1bf, b1, counts, lists, hbuf);
  gemm2_kernel<<<dim3(32, Dm / 128, Em), 256, 0, stream>>>(hbuf, w2bf, b2, gates, counts, lists, out);
}

// Round 2
// 1192.577 us; speedup vs baseline: 1.0925x; 1.0925x over previous
//
#include <hip/hip_runtime.h>
#include <stdint.h>

// Problem constants (B=2, S=2048 -> T=4096 tokens)
#define T_TOK 4096
#define Dm    1024
#define Em    8
#define Hm    4096

typedef __bf16 bf16x8 __attribute__((ext_vector_type(8)));
typedef float  f32x4  __attribute__((ext_vector_type(4)));

__device__ __forceinline__ unsigned short f2bf(float f) {
  union { float f; unsigned int u; } c; c.f = f;
  unsigned int u = c.u;
  unsigned int r = u + 0x7fffu + ((u >> 16) & 1u);  // round-to-nearest-even
  return (unsigned short)(r >> 16);
}
__device__ __forceinline__ float bf2f(unsigned short u) {
  union { unsigned int u; float f; } c; c.u = ((unsigned int)u) << 16; return c.f;
}

// async 16B/lane global->LDS copy (wave-uniform LDS base + lane*16)
__device__ __forceinline__ void async16(const void* g, void* l) {
  __builtin_amdgcn_global_load_lds(
      (const __attribute__((address_space(1))) void*)g,
      (__attribute__((address_space(3))) void*)l, 16, 0, 0);
}

// ---------------- transpose + fp32->bf16 convert ----------------
// src: [E][R][C] fp32, dst: [E][C][R] bf16.  grid (C/32, R/32, E), block (32,8)
__global__ void transpose_cvt_kernel(const float* __restrict__ src,
                                     unsigned short* __restrict__ dst,
                                     int R, int C) {
  __shared__ float tile[32][33];
  const int e = blockIdx.z;
  const float* s = src + (size_t)e * R * C;
  unsigned short* d = dst + (size_t)e * R * C;
  const int c0 = blockIdx.x * 32, r0 = blockIdx.y * 32;
  for (int i = threadIdx.y; i < 32; i += 8)
    tile[i][threadIdx.x] = s[(size_t)(r0 + i) * C + c0 + threadIdx.x];
  __syncthreads();
  for (int i = threadIdx.y; i < 32; i += 8)
    d[(size_t)(c0 + i) * R + r0 + threadIdx.x] = f2bf(tile[threadIdx.x][i]);
}

// ---------------- x fp32 -> bf16 (straight cast) ----------------
__global__ void cvt_x_kernel(const float* __restrict__ x, unsigned short* __restrict__ xbf) {
  const int i = blockIdx.x * 256 + threadIdx.x;     // over float4 units
  float4 v = ((const float4*)x)[i];
  ushort4 o;
  o.x = f2bf(v.x); o.y = f2bf(v.y); o.z = f2bf(v.z); o.w = f2bf(v.w);
  ((ushort4*)xbf)[i] = o;
}

// ---------------- router: one wave per token ----------------
__global__ __launch_bounds__(256) void router_kernel(
    const float* __restrict__ x, const float* __restrict__ noise,
    const float* __restrict__ Wr, const float* __restrict__ br,
    const float* __restrict__ Wn, const float* __restrict__ bn,
    float* __restrict__ out_gating, int* __restrict__ lists,
    int* __restrict__ counts, int* __restrict__ expt,
    int* __restrict__ pos, float* __restrict__ gsel) {
  const int wave = threadIdx.x >> 6, lane = threadIdx.x & 63;
  const int t = blockIdx.x * 4 + wave;
  const float* xt = x + (size_t)t * Dm;
  float accR[Em] = {}, accN[Em] = {};
  for (int d = lane; d < Dm; d += 64) {
    const float xv = xt[d];
    const float* wr = Wr + d * Em;
    const float* wn = Wn + d * Em;
#pragma unroll
    for (int e = 0; e < Em; e++) { accR[e] += xv * wr[e]; accN[e] += xv * wn[e]; }
  }
#pragma unroll
  for (int e = 0; e < Em; e++)
    for (int off = 32; off > 0; off >>= 1) {
      accR[e] += __shfl_down(accR[e], off, 64);
      accN[e] += __shfl_down(accN[e], off, 64);
    }
  if (lane == 0) {
    float lg[Em], ny[Em];
#pragma unroll
    for (int e = 0; e < Em; e++) {
      lg[e] = accR[e] + br[e];
      float nl = accN[e] + bn[e];
      float sp = fmaxf(nl, 0.f) + log1pf(expf(-fabsf(nl)));  // stable softplus
      ny[e] = lg[e] + noise[(size_t)t * Em + e] * sp;
    }
    // top-2, first-occurrence tie-break (matches lax.top_k)
    int i0 = 0;
#pragma unroll
    for (int e = 1; e < Em; e++) if (ny[e] > ny[i0]) i0 = e;
    int i1 = (i0 == 0) ? 1 : 0;
#pragma unroll
    for (int e = 0; e < Em; e++) if (e != i0 && ny[e] > ny[i1]) i1 = e;
    const float e1 = expf(ny[i1] - ny[i0]);
    const float g0 = 1.f / (1.f + e1), g1 = e1 / (1.f + e1);
    // dense softmax of clean logits (output 2)
    float m = lg[0];
#pragma unroll
    for (int e = 1; e < Em; e++) m = fmaxf(m, lg[e]);
    float s = 0.f;
#pragma unroll
    for (int e = 0; e < Em; e++) s += expf(lg[e] - m);
#pragma unroll
    for (int e = 0; e < Em; e++) out_gating[(size_t)t * Em + e] = expf(lg[e] - m) / s;
    // append to expert lists + inverse map
    int p0 = atomicAdd(&counts[i0], 1); lists[i0 * T_TOK + p0] = t;
    int p1 = atomicAdd(&counts[i1], 1); lists[i1 * T_TOK + p1] = t;
    expt[2 * t] = i0; expt[2 * t + 1] = i1;
    pos[2 * t] = p0;  pos[2 * t + 1] = p1;
    gsel[2 * t] = g0; gsel[2 * t + 1] = g1;
  }
}

// ---------------- GEMM1: hbuf[base+m][h] = relu(Xg[m] . W1t[h] + b1) ----------------
__global__ __launch_bounds__(256) void gemm1_kernel(
    const unsigned short* __restrict__ xbf, const unsigned short* __restrict__ w1bf,
    const float* __restrict__ b1, const int* __restrict__ counts,
    const int* __restrict__ lists, unsigned short* __restrict__ hbuf) {
  const int e = blockIdx.z;
  const int cnt = counts[e];
  const int m0 = blockIdx.x * 128;
  if (m0 >= cnt) return;
  const int n0 = blockIdx.y * 128;
  int base = 0;
  for (int i = 0; i < e; i++) base += counts[i];

  __shared__ __align__(16) unsigned short As[128 * 32];
  __shared__ __align__(16) unsigned short Bs[128 * 32];
  __shared__ int tok[128];

  const int tid = threadIdx.x;
  if (tid < 128) {
    int m = m0 + tid;
    tok[tid] = (m < cnt) ? lists[e * T_TOK + m] : 0;
  }
  __syncthreads();

  const int part = tid & 3;          // 16B chunk within 64B row
  const int r0 = tid >> 2;           // rows 0..63
  const int r1 = r0 + 64;
  const size_t gA0 = (size_t)tok[r0] * Dm + part * 8;
  const size_t gA1 = (size_t)tok[r1] * Dm + part * 8;
  const size_t gB0 = ((size_t)e * Hm + n0 + r0) * Dm + part * 8;
  const size_t gB1 = ((size_t)e * Hm + n0 + r1) * Dm + part * 8;

  const int lane = tid & 63, wv = tid >> 6;
  const int quad = lane >> 4, l15 = lane & 15;
  const int wm = (wv >> 1) * 64, wn = (wv & 1) * 64;

  // wave-uniform LDS bases for async copies (lane*16B implicit)
  unsigned short* a_l0 = As + wv * 512;          // rows 0..63
  unsigned short* a_l1 = As + 2048 + wv * 512;   // rows 64..127
  unsigned short* b_l0 = Bs + wv * 512;
  unsigned short* b_l1 = Bs + 2048 + wv * 512;

  f32x4 acc[4][4] = {};

  for (int k0 = 0; k0 < Dm; k0 += 32) {
    __syncthreads();                              // prev tile reads done
    async16(xbf + gA0 + k0, a_l0);
    async16(xbf + gA1 + k0, a_l1);
    async16(w1bf + gB0 + k0, b_l0);
    async16(w1bf + gB1 + k0, b_l1);
    __syncthreads();                              // copies complete
    bf16x8 af[4], bfv[4];
#pragma unroll
    for (int i = 0; i < 4; i++)
      af[i] = *(const bf16x8*)(As + (wm + i * 16 + l15) * 32 + quad * 8);
#pragma unroll
    for (int j = 0; j < 4; j++)
      bfv[j] = *(const bf16x8*)(Bs + (wn + j * 16 + l15) * 32 + quad * 8);
#pragma unroll
    for (int i = 0; i < 4; i++)
#pragma unroll
      for (int j = 0; j < 4; j++)
        acc[i][j] = __builtin_amdgcn_mfma_f32_16x16x32_bf16(af[i], bfv[j], acc[i][j], 0, 0, 0);
  }

#pragma unroll
  for (int i = 0; i < 4; i++)
#pragma unroll
    for (int r = 0; r < 4; r++) {
      const int ml = wm + i * 16 + quad * 4 + r;   // C/D row = quad*4+reg
      const int m = m0 + ml;
      if (m < cnt) {
#pragma unroll
        for (int j = 0; j < 4; j++) {
          const int n = n0 + wn + j * 16 + l15;    // C/D col = lane&15
          float v = acc[i][j][r] + b1[(size_t)e * Hm + n];
          v = fmaxf(v, 0.f);
          hbuf[(size_t)(base + m) * Hm + n] = f2bf(v);
        }
      }
    }
}

// ---------------- GEMM2: ybuf[base+m][d] = H[base+m] . W2t[d]  (no bias, no gate) ----------------
__global__ __launch_bounds__(256) void gemm2_kernel(
    const unsigned short* __restrict__ hbuf, const unsigned short* __restrict__ w2bf,
    const int* __restrict__ counts, float* __restrict__ ybuf) {
  const int e = blockIdx.z;
  const int cnt = counts[e];
  const int m0 = blockIdx.x * 128;
  if (m0 >= cnt) return;
  const int n0 = blockIdx.y * 128;   // N = 1024
  int base = 0;
  for (int i = 0; i < e; i++) base += counts[i];

  __shared__ __align__(16) unsigned short As[128 * 32];
  __shared__ __align__(16) unsigned short Bs[128 * 32];

  const int tid = threadIdx.x;
  const int part = tid & 3;
  const int r0 = tid >> 2;
  const int r1 = r0 + 64;
  const int rowA0 = min(base + m0 + r0, 2 * T_TOK - 1);  // clamp: tail rows read junk, unused
  const int rowA1 = min(base + m0 + r1, 2 * T_TOK - 1);
  const size_t gA0 = (size_t)rowA0 * Hm + part * 8;
  const size_t gA1 = (size_t)rowA1 * Hm + part * 8;
  const size_t gB0 = ((size_t)e * Dm + n0 + r0) * Hm + part * 8;
  const size_t gB1 = ((size_t)e * Dm + n0 + r1) * Hm + part * 8;

  const int lane = tid & 63, wv = tid >> 6;
  const int quad = lane >> 4, l15 = lane & 15;
  const int wm = (wv >> 1) * 64, wn = (wv & 1) * 64;

  unsigned short* a_l0 = As + wv * 512;
  unsigned short* a_l1 = As + 2048 + wv * 512;
  unsigned short* b_l0 = Bs + wv * 512;
  unsigned short* b_l1 = Bs + 2048 + wv * 512;

  f32x4 acc[4][4] = {};

  for (int k0 = 0; k0 < Hm; k0 += 32) {
    __syncthreads();
    async16(hbuf + gA0 + k0, a_l0);
    async16(hbuf + gA1 + k0, a_l1);
    async16(w2bf + gB0 + k0, b_l0);
    async16(w2bf + gB1 + k0, b_l1);
    __syncthreads();
    bf16x8 af[4], bfv[4];
#pragma unroll
    for (int i = 0; i < 4; i++)
      af[i] = *(const bf16x8*)(As + (wm + i * 16 + l15) * 32 + quad * 8);
#pragma unroll
    for (int j = 0; j < 4; j++)
      bfv[j] = *(const bf16x8*)(Bs + (wn + j * 16 + l15) * 32 + quad * 8);
#pragma unroll
    for (int i = 0; i < 4; i++)
#pragma unroll
      for (int j = 0; j < 4; j++)
        acc[i][j] = __builtin_amdgcn_mfma_f32_16x16x32_bf16(af[i], bfv[j], acc[i][j], 0, 0, 0);
  }

#pragma unroll
  for (int i = 0; i < 4; i++)
#pragma unroll
    for (int r = 0; r < 4; r++) {
      const int ml = wm + i * 16 + quad * 4 + r;
      const int m = m0 + ml;
      if (m < cnt) {
#pragma unroll
        for (int j = 0; j < 4; j++) {
          const int n = n0 + wn + j * 16 + l15;
          ybuf[(size_t)(base + m) * Dm + n] = acc[i][j][r];
        }
      }
    }
}

// ---------------- combine: out[t] = sum_k g_k * (ybuf[slot_k] + b2[e_k]) ----------------
__global__ __launch_bounds__(256) void combine_kernel(
    const float* __restrict__ ybuf, const float* __restrict__ b2,
    const int* __restrict__ counts, const int* __restrict__ expt,
    const int* __restrict__ pos, const float* __restrict__ gsel,
    float* __restrict__ out) {
  const int t = blockIdx.x;
  const int e0 = expt[2 * t], e1 = expt[2 * t + 1];
  const float g0 = gsel[2 * t], g1 = gsel[2 * t + 1];
  int b0 = 0, b1 = 0;
  for (int i = 0; i < e0; i++) b0 += counts[i];
  for (int i = 0; i < e1; i++) b1 += counts[i];
  const size_t s0 = (size_t)(b0 + pos[2 * t]) * Dm;
  const size_t s1 = (size_t)(b1 + pos[2 * t + 1]) * Dm;
  const int c = threadIdx.x * 4;
  float4 y0 = *(const float4*)(ybuf + s0 + c);
  float4 y1 = *(const float4*)(ybuf + s1 + c);
  float4 z0 = *(const float4*)(b2 + (size_t)e0 * Dm + c);
  float4 z1 = *(const float4*)(b2 + (size_t)e1 * Dm + c);
  float4 o;
  o.x = g0 * (y0.x + z0.x) + g1 * (y1.x + z1.x);
  o.y = g0 * (y0.y + z0.y) + g1 * (y1.y + z1.y);
  o.z = g0 * (y0.z + z0.z) + g1 * (y1.z + z1.z);
  o.w = g0 * (y0.w + z0.w) + g1 * (y1.w + z1.w);
  *(float4*)(out + (size_t)t * Dm + c) = o;
}

extern "C" void kernel_launch(void* const* d_in, const int* in_sizes, int n_in,
                              void* d_out, int out_size, void* d_ws, size_t ws_size,
                              hipStream_t stream) {
  const float* x     = (const float*)d_in[0];
  const float* noise = (const float*)d_in[1];
  const float* Wr    = (const float*)d_in[2];
  const float* br    = (const float*)d_in[3];
  const float* Wn    = (const float*)d_in[4];
  const float* bn    = (const float*)d_in[5];
  const float* W1    = (const float*)d_in[6];
  const float* b1    = (const float*)d_in[7];
  const float* W2    = (const float*)d_in[8];
  const float* b2    = (const float*)d_in[9];

  float* out        = (float*)d_out;
  float* out_gating = out + (size_t)T_TOK * Dm;

  // ws layout (~210 MB total)
  char* ws = (char*)d_ws;
  unsigned short* w1bf = (unsigned short*)(ws);                 //  64 MiB [E][H][D] bf16
  unsigned short* w2bf = (unsigned short*)(ws + 67108864);      //  64 MiB [E][D][H] bf16
  unsigned short* xbf  = (unsigned short*)(ws + 134217728);     //   8 MiB [T][D] bf16
  unsigned short* hbuf = (unsigned short*)(ws + 142606336);     //  64 MiB [2T][H] bf16
  float* ybuf          = (float*)(ws);                          //  32 MiB [2T][D] fp32, aliases w1bf (dead after gemm1)
  int*   lists         = (int*)(ws + 209715200);                // 128 KiB [E][T]
  int*   expt          = (int*)(ws + 209846272);                //  32 KiB [T][2]
  int*   pos           = (int*)(ws + 209879040);                //  32 KiB [T][2]
  float* gsel          = (float*)(ws + 209911808);              //  32 KiB [T][2]
  int*   counts        = (int*)(ws + 209944576);                //  32 B   [E]

  hipMemsetAsync(counts, 0, Em * sizeof(int), stream);

  // weights -> bf16 transposed (k-contiguous for MFMA B operand)
  transpose_cvt_kernel<<<dim3(Hm / 32, Dm / 32, Em), dim3(32, 8), 0, stream>>>(W1, w1bf, Dm, Hm);
  transpose_cvt_kernel<<<dim3(Dm / 32, Hm / 32, Em), dim3(32, 8), 0, stream>>>(W2, w2bf, Hm, Dm);
  cvt_x_kernel<<<(T_TOK * Dm / 4) / 256, 256, 0, stream>>>(x, xbf);

  router_kernel<<<T_TOK / 4, 256, 0, stream>>>(x, noise, Wr, br, Wn, bn,
                                               out_gating, lists, counts, expt, pos, gsel);

  gemm1_kernel<<<dim3(32, Hm / 128, Em), 256, 0, stream>>>(xbf, w1bf, b1, counts, lists, hbuf);
  gemm2_kernel<<<dim3(32, Dm / 128, Em), 256, 0, stream>>>(hbuf, w2bf, counts, ybuf);
  combine_kernel<<<T_TOK, 256, 0, stream>>>(ybuf, b2, counts, expt, pos, gsel, out);
}

// Round 3
// 871.515 us; speedup vs baseline: 1.4950x; 1.3684x over previous
//
#include <hip/hip_runtime.h>
#include <stdint.h>

// Problem constants (B=2, S=2048 -> T=4096 tokens)
#define T_TOK 4096
#define Dm    1024
#define Em    8
#define Hm    4096
#define NSLOT (2 * T_TOK)   // 8192 (token,expert) slots
#define KSPLIT 2            // gemm2 split-K factor

typedef __bf16 bf16x8 __attribute__((ext_vector_type(8)));
typedef float  f32x4  __attribute__((ext_vector_type(4)));

__device__ __forceinline__ unsigned short f2bf(float f) {
  union { float f; unsigned int u; } c; c.f = f;
  unsigned int u = c.u;
  unsigned int r = u + 0x7fffu + ((u >> 16) & 1u);  // round-to-nearest-even
  return (unsigned short)(r >> 16);
}

// async 16B/lane global->LDS copy (wave-uniform LDS base + lane*16)
__device__ __forceinline__ void async16(const void* g, void* l) {
  __builtin_amdgcn_global_load_lds(
      (const __attribute__((address_space(1))) void*)g,
      (__attribute__((address_space(3))) void*)l, 16, 0, 0);
}

// ---------------- transpose + fp32->bf16 convert ----------------
// src: [E][R][C] fp32, dst: [E][C][R] bf16.  grid (C/32, R/32, E), block (32,8)
__global__ void transpose_cvt_kernel(const float* __restrict__ src,
                                     unsigned short* __restrict__ dst,
                                     int R, int C) {
  __shared__ float tile[32][33];
  const int e = blockIdx.z;
  const float* s = src + (size_t)e * R * C;
  unsigned short* d = dst + (size_t)e * R * C;
  const int c0 = blockIdx.x * 32, r0 = blockIdx.y * 32;
  for (int i = threadIdx.y; i < 32; i += 8)
    tile[i][threadIdx.x] = s[(size_t)(r0 + i) * C + c0 + threadIdx.x];
  __syncthreads();
  for (int i = threadIdx.y; i < 32; i += 8)
    d[(size_t)(c0 + i) * R + r0 + threadIdx.x] = f2bf(tile[threadIdx.x][i]);
}

// ---------------- x fp32 -> bf16 (straight cast) ----------------
__global__ void cvt_x_kernel(const float* __restrict__ x, unsigned short* __restrict__ xbf) {
  const int i = blockIdx.x * 256 + threadIdx.x;     // over float4 units
  float4 v = ((const float4*)x)[i];
  ushort4 o;
  o.x = f2bf(v.x); o.y = f2bf(v.y); o.z = f2bf(v.z); o.w = f2bf(v.w);
  ((ushort4*)xbf)[i] = o;
}

// ---------------- router: one wave per token ----------------
__global__ __launch_bounds__(256) void router_kernel(
    const float* __restrict__ x, const float* __restrict__ noise,
    const float* __restrict__ Wr, const float* __restrict__ br,
    const float* __restrict__ Wn, const float* __restrict__ bn,
    float* __restrict__ out_gating, int* __restrict__ lists,
    int* __restrict__ counts, int* __restrict__ expt,
    int* __restrict__ pos, float* __restrict__ gsel) {
  const int wave = threadIdx.x >> 6, lane = threadIdx.x & 63;
  const int t = blockIdx.x * 4 + wave;
  const float* xt = x + (size_t)t * Dm;
  float accR[Em] = {}, accN[Em] = {};
  for (int d = lane; d < Dm; d += 64) {
    const float xv = xt[d];
    const float* wr = Wr + d * Em;
    const float* wn = Wn + d * Em;
#pragma unroll
    for (int e = 0; e < Em; e++) { accR[e] += xv * wr[e]; accN[e] += xv * wn[e]; }
  }
#pragma unroll
  for (int e = 0; e < Em; e++)
    for (int off = 32; off > 0; off >>= 1) {
      accR[e] += __shfl_down(accR[e], off, 64);
      accN[e] += __shfl_down(accN[e], off, 64);
    }
  if (lane == 0) {
    float lg[Em], ny[Em];
#pragma unroll
    for (int e = 0; e < Em; e++) {
      lg[e] = accR[e] + br[e];
      float nl = accN[e] + bn[e];
      float sp = fmaxf(nl, 0.f) + log1pf(expf(-fabsf(nl)));  // stable softplus
      ny[e] = lg[e] + noise[(size_t)t * Em + e] * sp;
    }
    // top-2, first-occurrence tie-break (matches lax.top_k)
    int i0 = 0;
#pragma unroll
    for (int e = 1; e < Em; e++) if (ny[e] > ny[i0]) i0 = e;
    int i1 = (i0 == 0) ? 1 : 0;
#pragma unroll
    for (int e = 0; e < Em; e++) if (e != i0 && ny[e] > ny[i1]) i1 = e;
    const float e1 = expf(ny[i1] - ny[i0]);
    const float g0 = 1.f / (1.f + e1), g1 = e1 / (1.f + e1);
    // dense softmax of clean logits (output 2)
    float m = lg[0];
#pragma unroll
    for (int e = 1; e < Em; e++) m = fmaxf(m, lg[e]);
    float s = 0.f;
#pragma unroll
    for (int e = 0; e < Em; e++) s += expf(lg[e] - m);
#pragma unroll
    for (int e = 0; e < Em; e++) out_gating[(size_t)t * Em + e] = expf(lg[e] - m) / s;
    // append to expert lists + inverse map
    int p0 = atomicAdd(&counts[i0], 1); lists[i0 * T_TOK + p0] = t;
    int p1 = atomicAdd(&counts[i1], 1); lists[i1 * T_TOK + p1] = t;
    expt[2 * t] = i0; expt[2 * t + 1] = i1;
    pos[2 * t] = p0;  pos[2 * t + 1] = p1;
    gsel[2 * t] = g0; gsel[2 * t + 1] = g1;
  }
}

// ---------------- GEMM1: hbuf[base+m][h] = relu(Xg[m] . W1t[h] + b1) ----------------
// double-buffered LDS + cross-iteration global_load_lds prefetch
__global__ __launch_bounds__(256) void gemm1_kernel(
    const unsigned short* __restrict__ xbf, const unsigned short* __restrict__ w1bf,
    const float* __restrict__ b1, const int* __restrict__ counts,
    const int* __restrict__ lists, unsigned short* __restrict__ hbuf) {
  const int e = blockIdx.z;
  const int cnt = counts[e];
  const int m0 = blockIdx.x * 128;
  if (m0 >= cnt) return;
  const int n0 = blockIdx.y * 128;
  int base = 0;
  for (int i = 0; i < e; i++) base += counts[i];

  __shared__ __align__(16) unsigned short As[2][128 * 32];
  __shared__ __align__(16) unsigned short Bs[2][128 * 32];
  __shared__ int tok[128];

  const int tid = threadIdx.x;
  if (tid < 128) {
    int m = m0 + tid;
    tok[tid] = (m < cnt) ? lists[e * T_TOK + m] : 0;
  }
  __syncthreads();

  const int part = tid & 3;          // 16B chunk within 64B row
  const int r0 = tid >> 2;           // rows 0..63
  const int r1 = r0 + 64;
  const size_t gA0 = (size_t)tok[r0] * Dm + part * 8;
  const size_t gA1 = (size_t)tok[r1] * Dm + part * 8;
  const size_t gB0 = ((size_t)e * Hm + n0 + r0) * Dm + part * 8;
  const size_t gB1 = ((size_t)e * Hm + n0 + r1) * Dm + part * 8;

  const int lane = tid & 63, wv = tid >> 6;
  const int quad = lane >> 4, l15 = lane & 15;
  const int wm = (wv >> 1) * 64, wn = (wv & 1) * 64;
  const int lds_off = wv * 512;      // wave-uniform base (lane*16B implicit)

  f32x4 acc[4][4] = {};

  // prologue: issue tile 0 into buf 0
  async16(xbf + gA0, As[0] + lds_off);
  async16(xbf + gA1, As[0] + 2048 + lds_off);
  async16(w1bf + gB0, Bs[0] + lds_off);
  async16(w1bf + gB1, Bs[0] + 2048 + lds_off);

  const int NI = Dm / 32;  // 32
  for (int it = 0; it < NI; it++) {
    const int cur = it & 1;
    __syncthreads();   // tile-it loads complete; prev reads of buf[cur^1] done
    if (it + 1 < NI) {
      const int k0 = (it + 1) * 32;
      const int nb = cur ^ 1;
      async16(xbf + gA0 + k0, As[nb] + lds_off);
      async16(xbf + gA1 + k0, As[nb] + 2048 + lds_off);
      async16(w1bf + gB0 + k0, Bs[nb] + lds_off);
      async16(w1bf + gB1 + k0, Bs[nb] + 2048 + lds_off);
    }
    bf16x8 af[4], bfv[4];
#pragma unroll
    for (int i = 0; i < 4; i++)
      af[i] = *(const bf16x8*)(As[cur] + (wm + i * 16 + l15) * 32 + quad * 8);
#pragma unroll
    for (int j = 0; j < 4; j++)
      bfv[j] = *(const bf16x8*)(Bs[cur] + (wn + j * 16 + l15) * 32 + quad * 8);
#pragma unroll
    for (int i = 0; i < 4; i++)
#pragma unroll
      for (int j = 0; j < 4; j++)
        acc[i][j] = __builtin_amdgcn_mfma_f32_16x16x32_bf16(af[i], bfv[j], acc[i][j], 0, 0, 0);
  }

#pragma unroll
  for (int i = 0; i < 4; i++)
#pragma unroll
    for (int r = 0; r < 4; r++) {
      const int ml = wm + i * 16 + quad * 4 + r;   // C/D row = quad*4+reg
      const int m = m0 + ml;
      if (m < cnt) {
#pragma unroll
        for (int j = 0; j < 4; j++) {
          const int n = n0 + wn + j * 16 + l15;    // C/D col = lane&15
          float v = acc[i][j][r] + b1[(size_t)e * Hm + n];
          v = fmaxf(v, 0.f);
          hbuf[(size_t)(base + m) * Hm + n] = f2bf(v);
        }
      }
    }
}

// ---------------- GEMM2 (split-K): ybuf[ks][base+m][d] = H[base+m] . W2t[d] over K-half ----------------
__global__ __launch_bounds__(256) void gemm2_kernel(
    const unsigned short* __restrict__ hbuf, const unsigned short* __restrict__ w2bf,
    const int* __restrict__ counts, float* __restrict__ ybuf) {
  const int e = blockIdx.z >> 1;
  const int ks = blockIdx.z & 1;
  const int cnt = counts[e];
  const int m0 = blockIdx.x * 128;
  if (m0 >= cnt) return;
  const int n0 = blockIdx.y * 128;   // N = 1024
  int base = 0;
  for (int i = 0; i < e; i++) base += counts[i];
  const int kbase = ks * (Hm / KSPLIT);  // 0 or 2048

  __shared__ __align__(16) unsigned short As[2][128 * 32];
  __shared__ __align__(16) unsigned short Bs[2][128 * 32];

  const int tid = threadIdx.x;
  const int part = tid & 3;
  const int r0 = tid >> 2;
  const int r1 = r0 + 64;
  const int rowA0 = min(base + m0 + r0, NSLOT - 1);  // clamp: tail rows read junk, unused
  const int rowA1 = min(base + m0 + r1, NSLOT - 1);
  const size_t gA0 = (size_t)rowA0 * Hm + kbase + part * 8;
  const size_t gA1 = (size_t)rowA1 * Hm + kbase + part * 8;
  const size_t gB0 = ((size_t)e * Dm + n0 + r0) * Hm + kbase + part * 8;
  const size_t gB1 = ((size_t)e * Dm + n0 + r1) * Hm + kbase + part * 8;

  const int lane = tid & 63, wv = tid >> 6;
  const int quad = lane >> 4, l15 = lane & 15;
  const int wm = (wv >> 1) * 64, wn = (wv & 1) * 64;
  const int lds_off = wv * 512;

  f32x4 acc[4][4] = {};

  async16(hbuf + gA0, As[0] + lds_off);
  async16(hbuf + gA1, As[0] + 2048 + lds_off);
  async16(w2bf + gB0, Bs[0] + lds_off);
  async16(w2bf + gB1, Bs[0] + 2048 + lds_off);

  const int NI = Hm / KSPLIT / 32;  // 64
  for (int it = 0; it < NI; it++) {
    const int cur = it & 1;
    __syncthreads();
    if (it + 1 < NI) {
      const int k0 = (it + 1) * 32;
      const int nb = cur ^ 1;
      async16(hbuf + gA0 + k0, As[nb] + lds_off);
      async16(hbuf + gA1 + k0, As[nb] + 2048 + lds_off);
      async16(w2bf + gB0 + k0, Bs[nb] + lds_off);
      async16(w2bf + gB1 + k0, Bs[nb] + 2048 + lds_off);
    }
    bf16x8 af[4], bfv[4];
#pragma unroll
    for (int i = 0; i < 4; i++)
      af[i] = *(const bf16x8*)(As[cur] + (wm + i * 16 + l15) * 32 + quad * 8);
#pragma unroll
    for (int j = 0; j < 4; j++)
      bfv[j] = *(const bf16x8*)(Bs[cur] + (wn + j * 16 + l15) * 32 + quad * 8);
#pragma unroll
    for (int i = 0; i < 4; i++)
#pragma unroll
      for (int j = 0; j < 4; j++)
        acc[i][j] = __builtin_amdgcn_mfma_f32_16x16x32_bf16(af[i], bfv[j], acc[i][j], 0, 0, 0);
  }

  float* yb = ybuf + (size_t)ks * NSLOT * Dm;
#pragma unroll
  for (int i = 0; i < 4; i++)
#pragma unroll
    for (int r = 0; r < 4; r++) {
      const int ml = wm + i * 16 + quad * 4 + r;
      const int m = m0 + ml;
      if (m < cnt) {
#pragma unroll
        for (int j = 0; j < 4; j++) {
          const int n = n0 + wn + j * 16 + l15;
          yb[(size_t)(base + m) * Dm + n] = acc[i][j][r];
        }
      }
    }
}

// ---------------- combine: out[t] = sum_k g_k * (ybuf0[slot_k]+ybuf1[slot_k] + b2[e_k]) ----------------
__global__ __launch_bounds__(256) void combine_kernel(
    const float* __restrict__ ybuf, const float* __restrict__ b2,
    const int* __restrict__ counts, const int* __restrict__ expt,
    const int* __restrict__ pos, const float* __restrict__ gsel,
    float* __restrict__ out) {
  const int t = blockIdx.x;
  const int e0 = expt[2 * t], e1 = expt[2 * t + 1];
  const float g0 = gsel[2 * t], g1 = gsel[2 * t + 1];
  int b0 = 0, b1 = 0;
  for (int i = 0; i < e0; i++) b0 += counts[i];
  for (int i = 0; i < e1; i++) b1 += counts[i];
  const size_t s0 = (size_t)(b0 + pos[2 * t]) * Dm;
  const size_t s1 = (size_t)(b1 + pos[2 * t + 1]) * Dm;
  const size_t half = (size_t)NSLOT * Dm;
  const int c = threadIdx.x * 4;
  float4 y0a = *(const float4*)(ybuf + s0 + c);
  float4 y0b = *(const float4*)(ybuf + half + s0 + c);
  float4 y1a = *(const float4*)(ybuf + s1 + c);
  float4 y1b = *(const float4*)(ybuf + half + s1 + c);
  float4 z0 = *(const float4*)(b2 + (size_t)e0 * Dm + c);
  float4 z1 = *(const float4*)(b2 + (size_t)e1 * Dm + c);
  float4 o;
  o.x = g0 * (y0a.x + y0b.x + z0.x) + g1 * (y1a.x + y1b.x + z1.x);
  o.y = g0 * (y0a.y + y0b.y + z0.y) + g1 * (y1a.y + y1b.y + z1.y);
  o.z = g0 * (y0a.z + y0b.z + z0.z) + g1 * (y1a.z + y1b.z + z1.z);
  o.w = g0 * (y0a.w + y0b.w + z0.w) + g1 * (y1a.w + y1b.w + z1.w);
  *(float4*)(out + (size_t)t * Dm + c) = o;
}

extern "C" void kernel_launch(void* const* d_in, const int* in_sizes, int n_in,
                              void* d_out, int out_size, void* d_ws, size_t ws_size,
                              hipStream_t stream) {
  const float* x     = (const float*)d_in[0];
  const float* noise = (const float*)d_in[1];
  const float* Wr    = (const float*)d_in[2];
  const float* br    = (const float*)d_in[3];
  const float* Wn    = (const float*)d_in[4];
  const float* bn    = (const float*)d_in[5];
  const float* W1    = (const float*)d_in[6];
  const float* b1    = (const float*)d_in[7];
  const float* W2    = (const float*)d_in[8];
  const float* b2    = (const float*)d_in[9];

  float* out        = (float*)d_out;
  float* out_gating = out + (size_t)T_TOK * Dm;

  // ws layout (~201 MB total)
  char* ws = (char*)d_ws;
  unsigned short* w1bf = (unsigned short*)(ws);                 //  64 MiB [E][H][D] bf16
  unsigned short* w2bf = (unsigned short*)(ws + 67108864);      //  64 MiB [E][D][H] bf16
  unsigned short* xbf  = (unsigned short*)(ws + 134217728);     //   8 MiB [T][D] bf16
  unsigned short* hbuf = (unsigned short*)(ws + 142606336);     //  64 MiB [2T][H] bf16
  float* ybuf          = (float*)(ws);                          //  64 MiB [2][2T][D] fp32, aliases w1bf (dead after gemm1)
  int*   lists         = (int*)(ws + 209715200);                // 128 KiB [E][T]
  int*   expt          = (int*)(ws + 209846272);                //  32 KiB [T][2]
  int*   pos           = (int*)(ws + 209879040);                //  32 KiB [T][2]
  float* gsel          = (float*)(ws + 209911808);              //  32 KiB [T][2]
  int*   counts        = (int*)(ws + 209944576);                //  32 B   [E]

  hipMemsetAsync(counts, 0, Em * sizeof(int), stream);

  // weights -> bf16 transposed (k-contiguous for MFMA B operand)
  transpose_cvt_kernel<<<dim3(Hm / 32, Dm / 32, Em), dim3(32, 8), 0, stream>>>(W1, w1bf, Dm, Hm);
  transpose_cvt_kernel<<<dim3(Dm / 32, Hm / 32, Em), dim3(32, 8), 0, stream>>>(W2, w2bf, Hm, Dm);
  cvt_x_kernel<<<(T_TOK * Dm / 4) / 256, 256, 0, stream>>>(x, xbf);

  router_kernel<<<T_TOK / 4, 256, 0, stream>>>(x, noise, Wr, br, Wn, bn,
                                               out_gating, lists, counts, expt, pos, gsel);

  // grid.x = 16 m-tiles: counts are ~1024 +/- ~30, 2048 cap is >17 sigma safe
  gemm1_kernel<<<dim3(16, Hm / 128, Em), 256, 0, stream>>>(xbf, w1bf, b1, counts, lists, hbuf);
  gemm2_kernel<<<dim3(16, Dm / 128, Em * KSPLIT), 256, 0, stream>>>(hbuf, w2bf, counts, ybuf);
  combine_kernel<<<T_TOK, 256, 0, stream>>>(ybuf, b2, counts, expt, pos, gsel, out);
}